// Round 13
// baseline (257.181 us; speedup 1.0000x reference)
//
#include <hip/hip_runtime.h>

// Sparse 3D conv (Cin=1, Cout=16), stride-2 — 27-plane two-pass.
//   pass 1: every entry: ONE bf16 store g[k][o] (no branches/atomics;
//           (o,k) unique by construction). 8 entries/thread for MLP.
//   pass 2: out[o,:] = sum_k g[k][o]*W[k,:]; 2 outputs/thread; weights
//           via compile-time k -> wave-uniform s_load (NO LDS tile).
//
// R11 lesson: LDS weight tile under (256,4) cap -> spill disaster. Keep
// s_load weights, plain stores. R6-R10 lessons: no sparse-path atomics,
// counters, or fusion barriers — branch-free 27-plane structure wins
// (R12 kernel budget ~134us vs ~154us for 8-plane+rescan variants).
// R12->R13: scatter27 4->8 entries/thread (R7 showed it miss-latency
// bound: 0.76 TB/s, VALU 3.4%, occ 77%; more independent misses/thread).

typedef float vf4 __attribute__((ext_vector_type(4)));
typedef int   vi4 __attribute__((ext_vector_type(4)));

__device__ inline unsigned short f32_to_bf16_rne(float x) {
    unsigned int u = __float_as_uint(x);
    unsigned int r = 0x7FFFu + ((u >> 16) & 1u);
    return (unsigned short)((u + r) >> 16);
}

__global__ void __launch_bounds__(256)
scatter27(const float* __restrict__ feats,
          const int* __restrict__ in_idx,
          const int* __restrict__ out_idx,
          const int* __restrict__ k_idx,
          unsigned short* __restrict__ g,
          int M, int np) {
    int t = blockIdx.x * blockDim.x + threadIdx.x;
    int base = t * 8;
    if (base + 7 < M) {
        vi4 kkA = *(const vi4*)&k_idx[base];
        vi4 kkB = *(const vi4*)&k_idx[base + 4];
        vi4 iiA = *(const vi4*)&in_idx[base];
        vi4 iiB = *(const vi4*)&in_idx[base + 4];
        vi4 ooA = *(const vi4*)&out_idx[base];
        vi4 ooB = *(const vi4*)&out_idx[base + 4];
        // 8 independent gathers in flight (MLP)
        float f0 = feats[iiA.x], f1 = feats[iiA.y],
              f2 = feats[iiA.z], f3 = feats[iiA.w];
        float f4 = feats[iiB.x], f5 = feats[iiB.y],
              f6 = feats[iiB.z], f7 = feats[iiB.w];
        // 32-bit plane addressing: k*np < 2^26
        unsigned a0 = (unsigned)kkA.x * (unsigned)np + (unsigned)ooA.x;
        unsigned a1 = (unsigned)kkA.y * (unsigned)np + (unsigned)ooA.y;
        unsigned a2 = (unsigned)kkA.z * (unsigned)np + (unsigned)ooA.z;
        unsigned a3 = (unsigned)kkA.w * (unsigned)np + (unsigned)ooA.w;
        unsigned a4 = (unsigned)kkB.x * (unsigned)np + (unsigned)ooB.x;
        unsigned a5 = (unsigned)kkB.y * (unsigned)np + (unsigned)ooB.y;
        unsigned a6 = (unsigned)kkB.z * (unsigned)np + (unsigned)ooB.z;
        unsigned a7 = (unsigned)kkB.w * (unsigned)np + (unsigned)ooB.w;
        g[a0] = f32_to_bf16_rne(f0);
        g[a1] = f32_to_bf16_rne(f1);
        g[a2] = f32_to_bf16_rne(f2);
        g[a3] = f32_to_bf16_rne(f3);
        g[a4] = f32_to_bf16_rne(f4);
        g[a5] = f32_to_bf16_rne(f5);
        g[a6] = f32_to_bf16_rne(f6);
        g[a7] = f32_to_bf16_rne(f7);
    } else if (base < M) {
        for (int m = base; m < M; ++m)
            g[(unsigned)k_idx[m] * (unsigned)np + (unsigned)out_idx[m]] =
                f32_to_bf16_rne(feats[in_idx[m]]);
    }
}

__global__ void __launch_bounds__(256, 4)
reduce27(const unsigned int* __restrict__ g32,  // 27 planes as u32 (2x bf16)
         const float* __restrict__ weight,      // [27][16] f32
         float* __restrict__ out,
         int n_out, int half_np) {
    int t = blockIdx.x * blockDim.x + threadIdx.x;
    int o0 = t * 2;
    if (o0 >= n_out) return;

    // 27 independent coalesced streams, kept packed (27 VGPRs)
    unsigned int gu[27];
    #pragma unroll
    for (int k = 0; k < 27; ++k)
        gu[k] = g32[(size_t)k * half_np + t];

    vf4 a0 = {0,0,0,0}, a1 = a0, a2 = a0, a3 = a0;
    vf4 b0 = a0, b1 = a0, b2 = a0, b3 = a0;
    #pragma unroll
    for (int k = 0; k < 27; ++k) {
        // compile-time k -> wave-uniform address -> s_load into SGPRs
        const vf4* w = (const vf4*)&weight[k * 16];
        vf4 w0 = w[0], w1 = w[1], w2 = w[2], w3 = w[3];
        float fa = __uint_as_float(gu[k] << 16);
        float fb = __uint_as_float(gu[k] & 0xFFFF0000u);
        a0 += fa * w0; a1 += fa * w1; a2 += fa * w2; a3 += fa * w3;
        b0 += fb * w0; b1 += fb * w1; b2 += fb * w2; b3 += fb * w3;
    }

    vf4* op = (vf4*)(out + (size_t)o0 * 16);
    op[0] = a0; op[1] = a1; op[2] = a2; op[3] = a3;   // coalesced 64B
    if (o0 + 1 < n_out) {
        op[4] = b0; op[5] = b1; op[6] = b2; op[7] = b3;
    }
}

// ---- fallback path (ws too small): known-correct atomic scatter ----
__global__ void __launch_bounds__(256)
sparse_conv_scatter_atomic(const float* __restrict__ feats,
                           const float* __restrict__ weight,
                           const int* __restrict__ in_idx,
                           const int* __restrict__ out_idx,
                           const int* __restrict__ k_idx,
                           float* __restrict__ out,
                           int M) {
    long long t = (long long)blockIdx.x * blockDim.x + threadIdx.x;
    int m = (int)(t >> 4);
    int c = (int)(t & 15);
    if (m >= M) return;
    float f = feats[in_idx[m]];
    float w = weight[k_idx[m] * 16 + c];
    atomicAdd(out + (long long)out_idx[m] * 16 + c, f * w);
}

extern "C" void kernel_launch(void* const* d_in, const int* in_sizes, int n_in,
                              void* d_out, int out_size, void* d_ws, size_t ws_size,
                              hipStream_t stream) {
    const float* feats  = (const float*)d_in[0];
    const float* weight = (const float*)d_in[1];
    const int*   in_idx = (const int*)d_in[2];
    const int*   out_idx= (const int*)d_in[3];
    const int*   k_idx  = (const int*)d_in[4];
    float*       out    = (float*)d_out;

    const int M     = in_sizes[2];        // rulebook length
    const int n_out = out_size / 16;      // out_size in FLOATS; rows of 16 f32
    const int np    = (n_out + 1) & ~1;   // even stride for u32-pair reads

    const size_t need = (size_t)27 * (size_t)np * sizeof(unsigned short); // ~105 MB
    const int block = 256;

    if (d_ws != nullptr && ws_size >= need) {
        unsigned short* g = (unsigned short*)d_ws;
        hipMemsetAsync(g, 0, need, stream);   // bf16 +0 == 0x0000

        const int nthr1 = (M + 7) / 8;
        const int grid1 = (nthr1 + block - 1) / block;
        scatter27<<<grid1, block, 0, stream>>>(feats, in_idx, out_idx,
                                               k_idx, g, M, np);

        const int nthr2 = (n_out + 1) / 2;
        const int grid2 = (nthr2 + block - 1) / block;
        reduce27<<<grid2, block, 0, stream>>>((const unsigned int*)g, weight,
                                              out, n_out, np / 2);
    } else {
        // d_out poisoned before every timed launch — zero it (out_size floats).
        hipMemsetAsync(d_out, 0, (size_t)out_size * sizeof(float), stream);
        const long long total = (long long)M * 16;
        const long long grid = (total + block - 1) / block;
        sparse_conv_scatter_atomic<<<(int)grid, block, 0, stream>>>(
            feats, weight, in_idx, out_idx, k_idx, out, M);
    }
}